// Round 2
// baseline (4593.168 us; speedup 1.0000x reference)
//
#include <hip/hip_runtime.h>

// ---------------------------------------------------------------------------
// GCN forward: 4 x (GEMM 128x128 + symmetric-norm aggregation) + mean-pool +
// final linear. All fp32. Channels C=128 hardcoded (vector float4 paths).
//
// Fusions:
//  - bias + ReLU of layer k applied while staging rows for layer k+1's GEMM
//  - self-loop term dinv^2 * (hW) written by the GEMM epilogue, so the
//    scatter kernel only has to add the E edge messages atomically
// ---------------------------------------------------------------------------

__global__ void k_count(const int* __restrict__ dstv, int E, int* __restrict__ cnt) {
    int e = blockIdx.x * blockDim.x + threadIdx.x;
    if (e < E) atomicAdd(&cnt[dstv[e]], 1);
}

__global__ void k_dinv(const int* __restrict__ cnt, int N, float* __restrict__ dinv) {
    int i = blockIdx.x * blockDim.x + threadIdx.x;
    if (i < N) dinv[i] = 1.0f / sqrtf((float)(cnt[i] + 1));  // +1 self loop, deg>=1
}

__global__ void k_norm(const int* __restrict__ src, const int* __restrict__ dstv,
                       const float* __restrict__ dinv, int E, float* __restrict__ nv) {
    int e = blockIdx.x * blockDim.x + threadIdx.x;
    if (e < E) nv[e] = dinv[src[e]] * dinv[dstv[e]];
}

__device__ __forceinline__ void fma4(float4& acc, float s, const float4& w) {
    acc.x = fmaf(s, w.x, acc.x);
    acc.y = fmaf(s, w.y, acc.y);
    acc.z = fmaf(s, w.z, acc.z);
    acc.w = fmaf(s, w.w, acc.w);
}

// out_tmp[r] = transform(In[r]) @ W ; agg[r] = dinv[r]^2 * out_tmp[r]
// transform = optional (+bias, relu) from the PREVIOUS layer.
// In may alias agg (in-place safe: each row read+written only by its own tile).
__global__ __launch_bounds__(256, 2) void k_gemm(
    const float* In, const float* __restrict__ W,
    const float* __restrict__ bias, int dorelu,
    const float* __restrict__ dinv,
    float* __restrict__ tmp, float* agg, int N)
{
    __shared__ float Wl[128 * 128];   // 64 KiB: full weight matrix [k][c]
    __shared__ float hl[16 * 132];    // 16 staged rows, stride 132 (pad: bank spread)
    const int tid = threadIdx.x;
    for (int i = tid; i < 4096; i += 256)
        ((float4*)Wl)[i] = ((const float4*)W)[i];

    const int cg = tid & 31;   // column group: cols 4cg..4cg+3
    const int rl = tid >> 5;   // rows rl and rl+8 of the tile
    const int tiles = (N + 15) >> 4;

    for (int tile = blockIdx.x; tile < tiles; tile += gridDim.x) {
        const int rowBase = tile << 4;
        __syncthreads();  // W visible (1st iter); hl readers done (later iters)
        for (int i = tid; i < 512; i += 256) {
            const int r = i >> 5, q = i & 31;
            const int row = rowBase + r;
            float4 v = make_float4(0.f, 0.f, 0.f, 0.f);
            if (row < N) v = *(const float4*)(In + (size_t)row * 128 + 4 * q);
            if (bias) {
                const float4 b = ((const float4*)bias)[q];
                v.x += b.x; v.y += b.y; v.z += b.z; v.w += b.w;
            }
            if (dorelu) {
                v.x = fmaxf(v.x, 0.f); v.y = fmaxf(v.y, 0.f);
                v.z = fmaxf(v.z, 0.f); v.w = fmaxf(v.w, 0.f);
            }
            *(float4*)(hl + r * 132 + 4 * q) = v;
        }
        __syncthreads();

        float4 a0 = make_float4(0.f, 0.f, 0.f, 0.f);
        float4 a1 = make_float4(0.f, 0.f, 0.f, 0.f);
        #pragma unroll 4
        for (int kq = 0; kq < 32; ++kq) {
            const float4 h0 = *(const float4*)(hl + rl * 132 + 4 * kq);
            const float4 h1 = *(const float4*)(hl + (rl + 8) * 132 + 4 * kq);
            const float4* wp = ((const float4*)Wl) + kq * 128 + cg;
            const float4 w0 = wp[0];
            const float4 w1 = wp[32];
            const float4 w2 = wp[64];
            const float4 w3 = wp[96];
            fma4(a0, h0.x, w0); fma4(a0, h0.y, w1); fma4(a0, h0.z, w2); fma4(a0, h0.w, w3);
            fma4(a1, h1.x, w0); fma4(a1, h1.y, w1); fma4(a1, h1.z, w2); fma4(a1, h1.w, w3);
        }

        const int row0 = rowBase + rl;
        const int row1 = row0 + 8;
        if (row0 < N) {
            *(float4*)(tmp + (size_t)row0 * 128 + 4 * cg) = a0;
            float dv = dinv[row0]; dv *= dv;
            float4 s0 = make_float4(a0.x * dv, a0.y * dv, a0.z * dv, a0.w * dv);
            *(float4*)(agg + (size_t)row0 * 128 + 4 * cg) = s0;
        }
        if (row1 < N) {
            *(float4*)(tmp + (size_t)row1 * 128 + 4 * cg) = a1;
            float dv = dinv[row1]; dv *= dv;
            float4 s1 = make_float4(a1.x * dv, a1.y * dv, a1.z * dv, a1.w * dv);
            *(float4*)(agg + (size_t)row1 * 128 + 4 * cg) = s1;
        }
    }
}

// agg[dst] += norm * tmp[src]   (32 threads x float4 per edge)
__global__ void k_scatter(const int* __restrict__ src, const int* __restrict__ dstv,
                          const float* __restrict__ nv, const float* __restrict__ tmp,
                          float* agg, int E)
{
    const int t = blockIdx.x * blockDim.x + threadIdx.x;
    const int q = t & 31;
    const int estride = (gridDim.x * blockDim.x) >> 5;
    for (int e = t >> 5; e < E; e += estride) {
        const int s = src[e];
        const int d = dstv[e];
        const float nrm = nv[e];
        const float4 v = *(const float4*)(tmp + (size_t)s * 128 + 4 * q);
        float* p = agg + (size_t)d * 128 + 4 * q;
        atomicAdd(p + 0, nrm * v.x);
        atomicAdd(p + 1, nrm * v.y);
        atomicAdd(p + 2, nrm * v.z);
        atomicAdd(p + 3, nrm * v.w);
    }
}

__global__ void k_pool(const float* __restrict__ h, const int* __restrict__ batch,
                       int N, float* pooled, float* gcnt)
{
    const int t = blockIdx.x * blockDim.x + threadIdx.x;
    const int q = t & 31;
    const int nstride = (gridDim.x * blockDim.x) >> 5;
    for (int n = t >> 5; n < N; n += nstride) {
        const int g = batch[n];
        const float4 v = *(const float4*)(h + (size_t)n * 128 + 4 * q);
        float* p = pooled + (size_t)g * 128 + 4 * q;
        atomicAdd(p + 0, v.x); atomicAdd(p + 1, v.y);
        atomicAdd(p + 2, v.z); atomicAdd(p + 3, v.w);
        if (q == 0) atomicAdd(&gcnt[g], 1.0f);
    }
}

// out[g][t] = (pooled[g]/cnt + b_last) . Wlin[:,t] + blin[t]
__global__ void k_final(const float* __restrict__ pooled, const float* __restrict__ gcnt,
                        const float* __restrict__ bias, const float* __restrict__ Wlin,
                        const float* __restrict__ blin, float* __restrict__ out, int T)
{
    __shared__ float hv[128];
    const int g = blockIdx.x;
    const int c = threadIdx.x;
    const float cntv = fmaxf(gcnt[g], 1.0f);
    hv[c] = pooled[(size_t)g * 128 + c] / cntv + bias[c];
    __syncthreads();
    if (c < T) {
        float acc = blin[c];
        #pragma unroll
        for (int k = 0; k < 128; ++k)
            acc = fmaf(hv[k], Wlin[k * T + c], acc);
        out[g * T + c] = acc;
    }
}

extern "C" void kernel_launch(void* const* d_in, const int* in_sizes, int n_in,
                              void* d_out, int out_size, void* d_ws, size_t ws_size,
                              hipStream_t stream)
{
    const float* x     = (const float*)d_in[0];
    const int*   ei    = (const int*)d_in[1];
    const int*   batch = (const int*)d_in[2];
    const float* W1    = (const float*)d_in[3];
    const float* b1    = (const float*)d_in[4];
    const float* Ws    = (const float*)d_in[5];
    const float* bs    = (const float*)d_in[6];
    const float* Wlin  = (const float*)d_in[7];
    const float* blin  = (const float*)d_in[8];
    float* out = (float*)d_out;

    const int N = in_sizes[0] / 128;
    const int E = in_sizes[1] / 2;
    const int T = in_sizes[8];           // 10
    const int G = out_size / T;          // 512

    // workspace layout (floats):
    // [cnt:int N][pooled G*128][gcnt G] <- zeroed each call | dinv N | nv E | tmp N*128 | bufA N*128
    float* ws     = (float*)d_ws;
    int*   cnt    = (int*)ws;
    float* pooled = ws + N;
    float* gcnt   = pooled + (size_t)G * 128;
    float* dinv   = gcnt + G;
    float* nv     = dinv + N;
    float* tmp    = nv + E;
    float* bufA   = tmp + (size_t)N * 128;

    const int* srcs = ei;
    const int* dsts = ei + E;

    hipMemsetAsync(d_ws, 0, (size_t)(N + (size_t)G * 128 + G) * sizeof(float), stream);

    k_count<<<(E + 255) / 256, 256, 0, stream>>>(dsts, E, cnt);
    k_dinv <<<(N + 255) / 256, 256, 0, stream>>>(cnt, N, dinv);
    k_norm <<<(E + 255) / 256, 256, 0, stream>>>(srcs, dsts, dinv, E, nv);

    // layer 1: tmp = x @ W1 ; bufA = dinv^2*tmp ; bufA += edge messages
    k_gemm   <<<1024, 256, 0, stream>>>(x, W1, nullptr, 0, dinv, tmp, bufA, N);
    k_scatter<<<2048, 256, 0, stream>>>(srcs, dsts, nv, tmp, bufA, E);
    // layer 2: input transform relu(v + b1)
    k_gemm   <<<1024, 256, 0, stream>>>(bufA, Ws + 0 * 16384, b1, 1, dinv, tmp, bufA, N);
    k_scatter<<<2048, 256, 0, stream>>>(srcs, dsts, nv, tmp, bufA, E);
    // layer 3: relu(v + bs[0])
    k_gemm   <<<1024, 256, 0, stream>>>(bufA, Ws + 1 * 16384, bs + 0 * 128, 1, dinv, tmp, bufA, N);
    k_scatter<<<2048, 256, 0, stream>>>(srcs, dsts, nv, tmp, bufA, E);
    // layer 4: relu(v + bs[1]); output stays pre-bias (bs[2] added in k_final)
    k_gemm   <<<1024, 256, 0, stream>>>(bufA, Ws + 2 * 16384, bs + 1 * 128, 1, dinv, tmp, bufA, N);
    k_scatter<<<2048, 256, 0, stream>>>(srcs, dsts, nv, tmp, bufA, E);

    k_pool <<<2048, 256, 0, stream>>>(bufA, batch, N, pooled, gcnt);
    k_final<<<G, 128, 0, stream>>>(pooled, gcnt, bs + 2 * 128, Wlin, blin, out, T);
}

// Round 3
// 483.948 us; speedup vs baseline: 9.4910x; 9.4910x over previous
//
#include <hip/hip_runtime.h>

// ---------------------------------------------------------------------------
// GCN forward, pull-based (atomic-free hot path):
//   build CSR by dst -> 4 x (GEMM 128x128 -> CSR gather) -> segmented mean
//   pool (batch is sorted) -> final linear. All fp32, C=128 float4 paths.
// ---------------------------------------------------------------------------

__global__ void k_count(const int* __restrict__ dstv, int E, int* __restrict__ cnt) {
    int e = blockIdx.x * blockDim.x + threadIdx.x;
    if (e < E) atomicAdd(&cnt[dstv[e]], 1);
}

__global__ void k_dinv(const int* __restrict__ cnt, int N, float* __restrict__ dinv) {
    int i = blockIdx.x * blockDim.x + threadIdx.x;
    if (i < N) dinv[i] = 1.0f / sqrtf((float)(cnt[i] + 1));  // +1 self loop
}

// --- exclusive scan of cnt[N] -> rowptr[N+1] (3 kernels, N<=256*256) -------
__global__ void k_scan1(const int* __restrict__ cnt, int N,
                        int* __restrict__ rowptr, int* __restrict__ bsums) {
    __shared__ int sh[256];
    const int t = threadIdx.x;
    const int i = blockIdx.x * 256 + t;
    const int v = (i < N) ? cnt[i] : 0;
    sh[t] = v;
    __syncthreads();
    for (int off = 1; off < 256; off <<= 1) {
        int add = (t >= off) ? sh[t - off] : 0;
        __syncthreads();
        sh[t] += add;
        __syncthreads();
    }
    if (i < N) rowptr[i] = sh[t] - v;          // block-local exclusive
    if (t == 255) bsums[blockIdx.x] = sh[255]; // block total
}

__global__ void k_scan2(int* __restrict__ bsums, int nb) {
    __shared__ int sh[256];
    const int t = threadIdx.x;
    const int v = (t < nb) ? bsums[t] : 0;
    sh[t] = v;
    __syncthreads();
    for (int off = 1; off < 256; off <<= 1) {
        int add = (t >= off) ? sh[t - off] : 0;
        __syncthreads();
        sh[t] += add;
        __syncthreads();
    }
    if (t < nb) bsums[t] = sh[t] - v;          // exclusive block offsets
}

__global__ void k_scan3(int* __restrict__ rowptr, const int* __restrict__ bsums,
                        int* __restrict__ cnt, int N, int E) {
    const int i = blockIdx.x * blockDim.x + threadIdx.x;
    if (i < N) {
        rowptr[i] += bsums[i >> 8];
        cnt[i] = 0;                            // becomes fill cursor
    }
    if (i == 0) rowptr[N] = E;
}

__global__ void k_fill(const int* __restrict__ srcv, const int* __restrict__ dstv,
                       const int* __restrict__ rowptr, int* __restrict__ cur,
                       int* __restrict__ csr_src, int E) {
    int e = blockIdx.x * blockDim.x + threadIdx.x;
    if (e < E) {
        const int d = dstv[e];
        const int slot = atomicAdd(&cur[d], 1);
        csr_src[rowptr[d] + slot] = srcv[e];
    }
}

// start[g] = first node index with batch[i] >= g   (batch sorted ascending)
__global__ void k_bounds(const int* __restrict__ batch, int N, int G,
                         int* __restrict__ start) {
    const int g = blockIdx.x * blockDim.x + threadIdx.x;
    if (g > G) return;
    int lo = 0, hi = N;
    while (lo < hi) {
        const int mid = (lo + hi) >> 1;
        if (batch[mid] < g) lo = mid + 1; else hi = mid;
    }
    start[g] = lo;
}

__device__ __forceinline__ void fma4(float4& acc, float s, const float4& w) {
    acc.x = fmaf(s, w.x, acc.x);
    acc.y = fmaf(s, w.y, acc.y);
    acc.z = fmaf(s, w.z, acc.z);
    acc.w = fmaf(s, w.w, acc.w);
}

// tmp[r] = transform(In[r]) @ W ; transform = (+bias, relu) of previous layer
__global__ __launch_bounds__(256, 2) void k_gemm(
    const float* __restrict__ In, const float* __restrict__ W,
    const float* __restrict__ bias, int dorelu,
    float* __restrict__ tmp, int N)
{
    __shared__ float Wl[128 * 128];   // full weight matrix [k][c]
    __shared__ float hl[16 * 132];    // 16 staged rows, stride 132
    const int tid = threadIdx.x;
    for (int i = tid; i < 4096; i += 256)
        ((float4*)Wl)[i] = ((const float4*)W)[i];

    const int cg = tid & 31;   // cols 4cg..4cg+3
    const int rl = tid >> 5;   // rows rl, rl+8
    const int tiles = (N + 15) >> 4;

    for (int tile = blockIdx.x; tile < tiles; tile += gridDim.x) {
        const int rowBase = tile << 4;
        __syncthreads();
        for (int i = tid; i < 512; i += 256) {
            const int r = i >> 5, q = i & 31;
            const int row = rowBase + r;
            float4 v = make_float4(0.f, 0.f, 0.f, 0.f);
            if (row < N) v = *(const float4*)(In + (size_t)row * 128 + 4 * q);
            if (bias) {
                const float4 b = ((const float4*)bias)[q];
                v.x += b.x; v.y += b.y; v.z += b.z; v.w += b.w;
            }
            if (dorelu) {
                v.x = fmaxf(v.x, 0.f); v.y = fmaxf(v.y, 0.f);
                v.z = fmaxf(v.z, 0.f); v.w = fmaxf(v.w, 0.f);
            }
            *(float4*)(hl + r * 132 + 4 * q) = v;
        }
        __syncthreads();

        float4 a0 = make_float4(0.f, 0.f, 0.f, 0.f);
        float4 a1 = make_float4(0.f, 0.f, 0.f, 0.f);
        #pragma unroll 4
        for (int kq = 0; kq < 32; ++kq) {
            const float4 h0 = *(const float4*)(hl + rl * 132 + 4 * kq);
            const float4 h1 = *(const float4*)(hl + (rl + 8) * 132 + 4 * kq);
            const float4* wp = ((const float4*)Wl) + kq * 128 + cg;
            const float4 w0 = wp[0];
            const float4 w1 = wp[32];
            const float4 w2 = wp[64];
            const float4 w3 = wp[96];
            fma4(a0, h0.x, w0); fma4(a0, h0.y, w1); fma4(a0, h0.z, w2); fma4(a0, h0.w, w3);
            fma4(a1, h1.x, w0); fma4(a1, h1.y, w1); fma4(a1, h1.z, w2); fma4(a1, h1.w, w3);
        }

        const int row0 = rowBase + rl;
        const int row1 = row0 + 8;
        if (row0 < N) *(float4*)(tmp + (size_t)row0 * 128 + 4 * cg) = a0;
        if (row1 < N) *(float4*)(tmp + (size_t)row1 * 128 + 4 * cg) = a1;
    }
}

// out[n] = dinv[n]^2 * tmp[n] + sum_{s in in(n)} dinv[s]*dinv[n] * tmp[s]
// one 32-lane group per node; each lane owns one float4 column slice
__global__ void k_gather(const int* __restrict__ rowptr, const int* __restrict__ csr_src,
                         const float* __restrict__ dinv, const float* __restrict__ tmp,
                         float* __restrict__ outb, int N)
{
    const int t = blockIdx.x * blockDim.x + threadIdx.x;
    const int lane = t & 31;
    const int n = t >> 5;
    if (n >= N) return;

    const int beg = rowptr[n];
    const int end = rowptr[n + 1];
    const float dn = dinv[n];

    float4 acc = *(const float4*)(tmp + (size_t)n * 128 + 4 * lane);
    const float selfw = dn * dn;
    acc.x *= selfw; acc.y *= selfw; acc.z *= selfw; acc.w *= selfw;

    for (int c = beg; c < end; c += 32) {
        int s = 0; float ds = 0.f;
        const int j = c + lane;
        if (j < end) { s = csr_src[j]; ds = dinv[s]; }
        const int m = min(32, end - c);
        for (int k = 0; k < m; ++k) {
            const int   sk = __shfl(s, k, 32);
            const float wk = __shfl(ds, k, 32) * dn;
            const float4 v = *(const float4*)(tmp + (size_t)sk * 128 + 4 * lane);
            fma4(acc, wk, v);
        }
    }
    *(float4*)(outb + (size_t)n * 128 + 4 * lane) = acc;
}

// one block per graph; rows start[g]..start[g+1] are contiguous (batch sorted)
__global__ void k_pool_seg(const float* __restrict__ h, const int* __restrict__ start,
                           float* __restrict__ pooled)
{
    __shared__ float4 sh[8][32];
    const int g = blockIdx.x;
    const int t = threadIdx.x;
    const int lane = t & 31, grp = t >> 5;
    const int s0 = start[g], s1 = start[g + 1];

    float4 acc = make_float4(0.f, 0.f, 0.f, 0.f);
    for (int r = s0 + grp; r < s1; r += 8) {
        const float4 v = *(const float4*)(h + (size_t)r * 128 + 4 * lane);
        acc.x += v.x; acc.y += v.y; acc.z += v.z; acc.w += v.w;
    }
    sh[grp][lane] = acc;
    __syncthreads();
    if (grp == 0) {
        float4 a = sh[0][lane];
        #pragma unroll
        for (int k = 1; k < 8; ++k) {
            a.x += sh[k][lane].x; a.y += sh[k][lane].y;
            a.z += sh[k][lane].z; a.w += sh[k][lane].w;
        }
        const float inv = 1.0f / fmaxf((float)(s1 - s0), 1.0f);
        a.x *= inv; a.y *= inv; a.z *= inv; a.w *= inv;
        *(float4*)(pooled + (size_t)g * 128 + 4 * lane) = a;
    }
}

// out[g][t] = (pooled[g] + b_last) . Wlin[:,t] + blin[t]
__global__ void k_final(const float* __restrict__ pooled,
                        const float* __restrict__ bias, const float* __restrict__ Wlin,
                        const float* __restrict__ blin, float* __restrict__ out, int T)
{
    __shared__ float hv[128];
    const int g = blockIdx.x;
    const int c = threadIdx.x;
    hv[c] = pooled[(size_t)g * 128 + c] + bias[c];
    __syncthreads();
    if (c < T) {
        float acc = blin[c];
        #pragma unroll
        for (int k = 0; k < 128; ++k)
            acc = fmaf(hv[k], Wlin[k * T + c], acc);
        out[g * T + c] = acc;
    }
}

extern "C" void kernel_launch(void* const* d_in, const int* in_sizes, int n_in,
                              void* d_out, int out_size, void* d_ws, size_t ws_size,
                              hipStream_t stream)
{
    const float* x     = (const float*)d_in[0];
    const int*   ei    = (const int*)d_in[1];
    const int*   batch = (const int*)d_in[2];
    const float* W1    = (const float*)d_in[3];
    const float* b1    = (const float*)d_in[4];
    const float* Ws    = (const float*)d_in[5];
    const float* bs    = (const float*)d_in[6];
    const float* Wlin  = (const float*)d_in[7];
    const float* blin  = (const float*)d_in[8];
    float* out = (float*)d_out;

    const int N = in_sizes[0] / 128;
    const int E = in_sizes[1] / 2;
    const int T = in_sizes[8];           // 10
    const int G = out_size / T;          // 512

    // workspace layout (floats, offsets padded to 16-float boundaries):
    float* ws = (float*)d_ws;
    int*   cnt     = (int*)ws;                       // [N]      histogram -> cursor
    int*   rowptr  = (int*)(ws + 50000);             // [N+1]
    int*   bsums   = (int*)(ws + 100016);            // [256]
    int*   start   = (int*)(ws + 100272);            // [G+1]
    int*   csr_src = (int*)(ws + 100800);            // [E]
    float* dinv    = ws + 740800;                    // [N]
    float* tmp     = ws + 790800;                    // [N*128]
    float* bufA    = ws + 7190800;                   // [N*128]
    float* pooled  = ws + 13590800;                  // [G*128]

    const int* srcs = ei;
    const int* dsts = ei + E;

    hipMemsetAsync(cnt, 0, (size_t)N * sizeof(int), stream);

    const int nb = (N + 255) / 256;   // 196 scan blocks
    k_count<<<(E + 255) / 256, 256, 0, stream>>>(dsts, E, cnt);
    k_dinv <<<nb, 256, 0, stream>>>(cnt, N, dinv);
    k_scan1<<<nb, 256, 0, stream>>>(cnt, N, rowptr, bsums);
    k_scan2<<<1, 256, 0, stream>>>(bsums, nb);
    k_scan3<<<nb, 256, 0, stream>>>(rowptr, bsums, cnt, N, E);
    k_fill <<<(E + 255) / 256, 256, 0, stream>>>(srcs, dsts, rowptr, cnt, csr_src, E);
    k_bounds<<<(G + 256) / 256, 256, 0, stream>>>(batch, N, G, start);

    const int gatherBlocks = (N * 32 + 255) / 256;

    // layer 1
    k_gemm  <<<1024, 256, 0, stream>>>(x, W1, nullptr, 0, tmp, N);
    k_gather<<<gatherBlocks, 256, 0, stream>>>(rowptr, csr_src, dinv, tmp, bufA, N);
    // layer 2 (relu(v + b1) applied on load)
    k_gemm  <<<1024, 256, 0, stream>>>(bufA, Ws + 0 * 16384, b1, 1, tmp, N);
    k_gather<<<gatherBlocks, 256, 0, stream>>>(rowptr, csr_src, dinv, tmp, bufA, N);
    // layer 3
    k_gemm  <<<1024, 256, 0, stream>>>(bufA, Ws + 1 * 16384, bs + 0 * 128, 1, tmp, N);
    k_gather<<<gatherBlocks, 256, 0, stream>>>(rowptr, csr_src, dinv, tmp, bufA, N);
    // layer 4 (bs[2] deferred to k_final)
    k_gemm  <<<1024, 256, 0, stream>>>(bufA, Ws + 2 * 16384, bs + 1 * 128, 1, tmp, N);
    k_gather<<<gatherBlocks, 256, 0, stream>>>(rowptr, csr_src, dinv, tmp, bufA, N);

    k_pool_seg<<<G, 256, 0, stream>>>(bufA, start, pooled);
    k_final   <<<G, 128, 0, stream>>>(pooled, bs + 2 * 128, Wlin, blin, out, T);
}

// Round 4
// 422.592 us; speedup vs baseline: 10.8690x; 1.1452x over previous
//
#include <hip/hip_runtime.h>

// ---------------------------------------------------------------------------
// GCN forward, pull-based + fused. Using A(HW) = (AH)W:
//   per layer: one kernel gathers A·H rows into LDS and immediately applies
//   the 128x128 matvec (W resident in LDS), epilogue bias+relu.
//   Layer 4's matvec commutes past the mean-pool: out = mean(agg4)·(W4·Wlin)
//   + (b4·Wlin + blin), so layer 4 is a pure gather.
// ---------------------------------------------------------------------------

__global__ void k_count(const int* __restrict__ dstv, int E, int* __restrict__ cnt) {
    int e = blockIdx.x * blockDim.x + threadIdx.x;
    if (e < E) atomicAdd(&cnt[dstv[e]], 1);
}

// scan1 also emits dinv (cnt still pristine here)
__global__ void k_scan1(const int* __restrict__ cnt, int N,
                        int* __restrict__ rowptr, int* __restrict__ bsums,
                        float* __restrict__ dinv) {
    __shared__ int sh[256];
    const int t = threadIdx.x;
    const int i = blockIdx.x * 256 + t;
    const int v = (i < N) ? cnt[i] : 0;
    if (i < N) dinv[i] = 1.0f / sqrtf((float)(v + 1));  // +1 self loop
    sh[t] = v;
    __syncthreads();
    for (int off = 1; off < 256; off <<= 1) {
        int add = (t >= off) ? sh[t - off] : 0;
        __syncthreads();
        sh[t] += add;
        __syncthreads();
    }
    if (i < N) rowptr[i] = sh[t] - v;
    if (t == 255) bsums[blockIdx.x] = sh[255];
}

__global__ void k_scan2(int* __restrict__ bsums, int nb) {
    __shared__ int sh[256];
    const int t = threadIdx.x;
    const int v = (t < nb) ? bsums[t] : 0;
    sh[t] = v;
    __syncthreads();
    for (int off = 1; off < 256; off <<= 1) {
        int add = (t >= off) ? sh[t - off] : 0;
        __syncthreads();
        sh[t] += add;
        __syncthreads();
    }
    if (t < nb) bsums[t] = sh[t] - v;
}

__global__ void k_scan3(int* __restrict__ rowptr, const int* __restrict__ bsums,
                        int* __restrict__ cnt, int N, int E) {
    const int i = blockIdx.x * blockDim.x + threadIdx.x;
    if (i < N) {
        rowptr[i] += bsums[i >> 8];
        cnt[i] = 0;                            // becomes fill cursor
    }
    if (i == 0) rowptr[N] = E;
}

__global__ void k_fill(const int* __restrict__ srcv, const int* __restrict__ dstv,
                       const int* __restrict__ rowptr, int* __restrict__ cur,
                       int* __restrict__ csr_src, int E) {
    int e = blockIdx.x * blockDim.x + threadIdx.x;
    if (e < E) {
        const int d = dstv[e];
        const int slot = atomicAdd(&cur[d], 1);
        csr_src[rowptr[d] + slot] = srcv[e];
    }
}

__global__ void k_bounds(const int* __restrict__ batch, int N, int G,
                         int* __restrict__ start) {
    const int g = blockIdx.x * blockDim.x + threadIdx.x;
    if (g > G) return;
    int lo = 0, hi = N;
    while (lo < hi) {
        const int mid = (lo + hi) >> 1;
        if (batch[mid] < g) lo = mid + 1; else hi = mid;
    }
    start[g] = lo;
}

// Wc = W4 @ Wlin (128 x T), bc = b4 @ Wlin + blin (T)
__global__ void k_combine(const float* __restrict__ W4, const float* __restrict__ Wlin,
                          const float* __restrict__ b4, const float* __restrict__ blin,
                          float* __restrict__ Wc, float* __restrict__ bc, int T) {
    const int idx = blockIdx.x * blockDim.x + threadIdx.x;
    if (idx < 128 * T) {
        const int k = idx / T, t = idx % T;
        float acc = 0.f;
        #pragma unroll 8
        for (int j = 0; j < 128; ++j)
            acc = fmaf(W4[k * 128 + j], Wlin[j * T + t], acc);
        Wc[idx] = acc;
    }
    if (idx < T) {
        float acc = blin[idx];
        #pragma unroll 8
        for (int j = 0; j < 128; ++j)
            acc = fmaf(b4[j], Wlin[j * T + idx], acc);
        bc[idx] = acc;
    }
}

__device__ __forceinline__ void fma4(float4& acc, float s, const float4& w) {
    acc.x = fmaf(s, w.x, acc.x);
    acc.y = fmaf(s, w.y, acc.y);
    acc.z = fmaf(s, w.z, acc.z);
    acc.w = fmaf(s, w.w, acc.w);
}

// aggregated row n, column slice [4*lane, 4*lane+4):
//   dn * ( dn*Hin[n] + sum_s dinv[s]*Hin[s] )
__device__ __forceinline__ float4 gather_row(
    int n, const float* __restrict__ Hin,
    const int* __restrict__ rowptr, const int* __restrict__ csr_src,
    const float* __restrict__ dinv, int lane)
{
    const float dn = dinv[n];
    const float4 self = *(const float4*)(Hin + (size_t)n * 128 + 4 * lane);
    float4 a0 = make_float4(self.x * dn, self.y * dn, self.z * dn, self.w * dn);
    float4 a1 = make_float4(0.f, 0.f, 0.f, 0.f);
    float4 a2 = a1, a3 = a1;
    const int beg = rowptr[n], end = rowptr[n + 1];
    for (int c = beg; c < end; c += 32) {
        const int j = c + lane;
        int s = 0; float dsv = 0.f;
        if (j < end) { s = csr_src[j]; dsv = dinv[s]; }
        const int m = min(32, end - c);
        int k = 0;
        for (; k + 4 <= m; k += 4) {
            const int   i0 = __shfl(s, k, 32),   i1 = __shfl(s, k + 1, 32);
            const int   i2 = __shfl(s, k + 2, 32), i3 = __shfl(s, k + 3, 32);
            const float w0 = __shfl(dsv, k, 32),   w1 = __shfl(dsv, k + 1, 32);
            const float w2 = __shfl(dsv, k + 2, 32), w3 = __shfl(dsv, k + 3, 32);
            const float4 v0 = *(const float4*)(Hin + (size_t)i0 * 128 + 4 * lane);
            const float4 v1 = *(const float4*)(Hin + (size_t)i1 * 128 + 4 * lane);
            const float4 v2 = *(const float4*)(Hin + (size_t)i2 * 128 + 4 * lane);
            const float4 v3 = *(const float4*)(Hin + (size_t)i3 * 128 + 4 * lane);
            fma4(a0, w0, v0); fma4(a1, w1, v1); fma4(a2, w2, v2); fma4(a3, w3, v3);
        }
        for (; k < m; ++k) {
            const int   i0 = __shfl(s, k, 32);
            const float w0 = __shfl(dsv, k, 32);
            const float4 v0 = *(const float4*)(Hin + (size_t)i0 * 128 + 4 * lane);
            fma4(a0, w0, v0);
        }
    }
    a0.x += a1.x + a2.x + a3.x;
    a0.y += a1.y + a2.y + a3.y;
    a0.z += a1.z + a2.z + a3.z;
    a0.w += a1.w + a2.w + a3.w;
    return make_float4(a0.x * dn, a0.y * dn, a0.z * dn, a0.w * dn);
}

// Fused layer: Hout[n] = act( (A·Hin)[n] @ W + bias )
__global__ __launch_bounds__(256, 2) void k_layer(
    const float* __restrict__ Hin, const float* __restrict__ W,
    const float* __restrict__ bias, int dorelu,
    const int* __restrict__ rowptr, const int* __restrict__ csr_src,
    const float* __restrict__ dinv,
    float* __restrict__ Hout, int N)
{
    __shared__ float Wl[128 * 128];   // 64 KiB weights
    __shared__ float hl[16 * 132];    // 16 aggregated rows, stride 132
    const int tid = threadIdx.x;
    for (int i = tid; i < 4096; i += 256)
        ((float4*)Wl)[i] = ((const float4*)W)[i];

    const int lane = tid & 31;
    const int grp  = tid >> 5;        // 0..7
    const int tiles = (N + 15) >> 4;

    for (int tile = blockIdx.x; tile < tiles; tile += gridDim.x) {
        const int rowBase = tile << 4;
        __syncthreads();  // prev matvec's hl readers done
        {
            const int n0 = rowBase + grp;
            if (n0 < N) {
                const float4 g0 = gather_row(n0, Hin, rowptr, csr_src, dinv, lane);
                *(float4*)(hl + grp * 132 + 4 * lane) = g0;
            }
            const int n1 = rowBase + grp + 8;
            if (n1 < N) {
                const float4 g1 = gather_row(n1, Hin, rowptr, csr_src, dinv, lane);
                *(float4*)(hl + (grp + 8) * 132 + 4 * lane) = g1;
            }
        }
        __syncthreads();  // hl (and W on first iter) ready

        float4 a0 = make_float4(0.f, 0.f, 0.f, 0.f);
        float4 a1 = make_float4(0.f, 0.f, 0.f, 0.f);
        #pragma unroll 4
        for (int kq = 0; kq < 32; ++kq) {
            const float4 h0 = *(const float4*)(hl + grp * 132 + 4 * kq);
            const float4 h1 = *(const float4*)(hl + (grp + 8) * 132 + 4 * kq);
            const float4* wp = ((const float4*)Wl) + kq * 128 + lane;
            const float4 w0 = wp[0];
            const float4 w1 = wp[32];
            const float4 w2 = wp[64];
            const float4 w3 = wp[96];
            fma4(a0, h0.x, w0); fma4(a0, h0.y, w1); fma4(a0, h0.z, w2); fma4(a0, h0.w, w3);
            fma4(a1, h1.x, w0); fma4(a1, h1.y, w1); fma4(a1, h1.z, w2); fma4(a1, h1.w, w3);
        }

        const float4 bv = ((const float4*)bias)[lane];
        a0.x += bv.x; a0.y += bv.y; a0.z += bv.z; a0.w += bv.w;
        a1.x += bv.x; a1.y += bv.y; a1.z += bv.z; a1.w += bv.w;
        if (dorelu) {
            a0.x = fmaxf(a0.x, 0.f); a0.y = fmaxf(a0.y, 0.f);
            a0.z = fmaxf(a0.z, 0.f); a0.w = fmaxf(a0.w, 0.f);
            a1.x = fmaxf(a1.x, 0.f); a1.y = fmaxf(a1.y, 0.f);
            a1.z = fmaxf(a1.z, 0.f); a1.w = fmaxf(a1.w, 0.f);
        }
        const int row0 = rowBase + grp;
        const int row1 = row0 + 8;
        if (row0 < N) *(float4*)(Hout + (size_t)row0 * 128 + 4 * lane) = a0;
        if (row1 < N) *(float4*)(Hout + (size_t)row1 * 128 + 4 * lane) = a1;
    }
}

// Layer 4: pure gather (matvec commuted past the mean-pool)
__global__ void k_gather4(const int* __restrict__ rowptr, const int* __restrict__ csr_src,
                          const float* __restrict__ dinv, const float* __restrict__ Hin,
                          float* __restrict__ outb, int N)
{
    const int t = blockIdx.x * blockDim.x + threadIdx.x;
    const int lane = t & 31;
    const int n = t >> 5;
    if (n >= N) return;
    const float4 r = gather_row(n, Hin, rowptr, csr_src, dinv, lane);
    *(float4*)(outb + (size_t)n * 128 + 4 * lane) = r;
}

__global__ void k_pool_seg(const float* __restrict__ h, const int* __restrict__ start,
                           float* __restrict__ pooled)
{
    __shared__ float4 sh[8][32];
    const int g = blockIdx.x;
    const int t = threadIdx.x;
    const int lane = t & 31, grp = t >> 5;
    const int s0 = start[g], s1 = start[g + 1];

    float4 acc = make_float4(0.f, 0.f, 0.f, 0.f);
    for (int r = s0 + grp; r < s1; r += 8) {
        const float4 v = *(const float4*)(h + (size_t)r * 128 + 4 * lane);
        acc.x += v.x; acc.y += v.y; acc.z += v.z; acc.w += v.w;
    }
    sh[grp][lane] = acc;
    __syncthreads();
    if (grp == 0) {
        float4 a = sh[0][lane];
        #pragma unroll
        for (int k = 1; k < 8; ++k) {
            a.x += sh[k][lane].x; a.y += sh[k][lane].y;
            a.z += sh[k][lane].z; a.w += sh[k][lane].w;
        }
        const float inv = 1.0f / fmaxf((float)(s1 - s0), 1.0f);
        a.x *= inv; a.y *= inv; a.z *= inv; a.w *= inv;
        *(float4*)(pooled + (size_t)g * 128 + 4 * lane) = a;
    }
}

// out[g][t] = pooledA[g] . Wc[:,t] + bc[t]
__global__ void k_final(const float* __restrict__ pooledA, const float* __restrict__ Wc,
                        const float* __restrict__ bc, float* __restrict__ out, int T)
{
    __shared__ float hv[128];
    const int g = blockIdx.x;
    const int c = threadIdx.x;
    hv[c] = pooledA[(size_t)g * 128 + c];
    __syncthreads();
    if (c < T) {
        float acc = bc[c];
        #pragma unroll
        for (int k = 0; k < 128; ++k)
            acc = fmaf(hv[k], Wc[k * T + c], acc);
        out[g * T + c] = acc;
    }
}

extern "C" void kernel_launch(void* const* d_in, const int* in_sizes, int n_in,
                              void* d_out, int out_size, void* d_ws, size_t ws_size,
                              hipStream_t stream)
{
    const float* x     = (const float*)d_in[0];
    const int*   ei    = (const int*)d_in[1];
    const int*   batch = (const int*)d_in[2];
    const float* W1    = (const float*)d_in[3];
    const float* b1    = (const float*)d_in[4];
    const float* Ws    = (const float*)d_in[5];
    const float* bs    = (const float*)d_in[6];
    const float* Wlin  = (const float*)d_in[7];
    const float* blin  = (const float*)d_in[8];
    float* out = (float*)d_out;

    const int N = in_sizes[0] / 128;
    const int E = in_sizes[1] / 2;
    const int T = in_sizes[8];           // 10
    const int G = out_size / T;          // 512

    // workspace layout (float offsets):
    float* ws = (float*)d_ws;
    int*   cnt     = (int*)ws;                       // [N] histogram -> cursor (dead after fill)
    int*   rowptr  = (int*)(ws + 50000);             // [N+1]
    int*   bsums   = (int*)(ws + 100016);            // [256]
    int*   start   = (int*)(ws + 100272);            // [G+1]
    int*   csr_src = (int*)(ws + 100800);            // [E]
    float* dinv    = ws + 740800;                    // [N]
    float* bufA    = ws + 790800;                    // [N*128]
    float* bufB    = ws + 7190800;                   // [N*128]
    float* pooledA = ws + 13590800;                  // [G*128]
    float* Wc      = ws + 24000;                     // reuse cnt region (dead), [128*T]
    float* bc      = ws + 24000 + 128 * 10;          // [T]

    const int* srcs = ei;
    const int* dsts = ei + E;
    const float* W4 = Ws + 2 * 16384;
    const float* b4 = bs + 2 * 128;

    hipMemsetAsync(cnt, 0, (size_t)N * sizeof(int), stream);

    const int nb = (N + 255) / 256;
    k_count <<<(E + 255) / 256, 256, 0, stream>>>(dsts, E, cnt);
    k_scan1 <<<nb, 256, 0, stream>>>(cnt, N, rowptr, bsums, dinv);
    k_scan2 <<<1, 256, 0, stream>>>(bsums, nb);
    k_scan3 <<<nb, 256, 0, stream>>>(rowptr, bsums, cnt, N, E);
    k_fill  <<<(E + 255) / 256, 256, 0, stream>>>(srcs, dsts, rowptr, cnt, csr_src, E);
    k_bounds<<<(G + 256) / 256, 256, 0, stream>>>(batch, N, G, start);
    // cnt region dead from here; Wc/bc overlap it (k_combine runs after k_fill)
    k_combine<<<(128 * T + 255) / 256, 256, 0, stream>>>(W4, Wlin, b4, blin, Wc, bc, T);

    // layers 1-3 fused gather+matvec; ping-pong buffers
    k_layer<<<1024, 256, 0, stream>>>(x,    W1,          b1,       1, rowptr, csr_src, dinv, bufA, N);
    k_layer<<<1024, 256, 0, stream>>>(bufA, Ws,          bs,       1, rowptr, csr_src, dinv, bufB, N);
    k_layer<<<1024, 256, 0, stream>>>(bufB, Ws + 16384,  bs + 128, 1, rowptr, csr_src, dinv, bufA, N);
    // layer 4: gather only
    k_gather4<<<(N * 32 + 255) / 256, 256, 0, stream>>>(rowptr, csr_src, dinv, bufA, bufB, N);

    k_pool_seg<<<G, 256, 0, stream>>>(bufB, start, pooledA);
    k_final   <<<G, 128, 0, stream>>>(pooledA, Wc, bc, out, T);
}

// Round 5
// 369.272 us; speedup vs baseline: 12.4384x; 1.1444x over previous
//
#include <hip/hip_runtime.h>

// ---------------------------------------------------------------------------
// GCN forward, pull-based + fused. A(HW) = (AH)W:
//   per layer one kernel: pair-gather A·H rows into LDS, then 128x128 matvec
//   (W resident in LDS), epilogue bias+relu. Layer 4's matvec commutes past
//   the mean-pool: out = mean(agg4)·(W4·Wlin) + (b4·Wlin + blin).
// 512-thread blocks, 80 KiB LDS -> exactly 2 blocks/CU (160 KiB), 16 waves/CU.
// ---------------------------------------------------------------------------

__global__ void k_count(const int* __restrict__ dstv, int E, int* __restrict__ cnt) {
    int e = blockIdx.x * blockDim.x + threadIdx.x;
    if (e < E) atomicAdd(&cnt[dstv[e]], 1);
}

// scan1 also emits dinv (cnt still pristine here)
__global__ void k_scan1(const int* __restrict__ cnt, int N,
                        int* __restrict__ rowptr, int* __restrict__ bsums,
                        float* __restrict__ dinv) {
    __shared__ int sh[256];
    const int t = threadIdx.x;
    const int i = blockIdx.x * 256 + t;
    const int v = (i < N) ? cnt[i] : 0;
    if (i < N) dinv[i] = 1.0f / sqrtf((float)(v + 1));  // +1 self loop
    sh[t] = v;
    __syncthreads();
    for (int off = 1; off < 256; off <<= 1) {
        int add = (t >= off) ? sh[t - off] : 0;
        __syncthreads();
        sh[t] += add;
        __syncthreads();
    }
    if (i < N) rowptr[i] = sh[t] - v;
    if (t == 255) bsums[blockIdx.x] = sh[255];
}

__global__ void k_scan2(int* __restrict__ bsums, int nb) {
    __shared__ int sh[256];
    const int t = threadIdx.x;
    const int v = (t < nb) ? bsums[t] : 0;
    sh[t] = v;
    __syncthreads();
    for (int off = 1; off < 256; off <<= 1) {
        int add = (t >= off) ? sh[t - off] : 0;
        __syncthreads();
        sh[t] += add;
        __syncthreads();
    }
    if (t < nb) bsums[t] = sh[t] - v;
}

__global__ void k_scan3(int* __restrict__ rowptr, const int* __restrict__ bsums,
                        int* __restrict__ cnt, int N, int E) {
    const int i = blockIdx.x * blockDim.x + threadIdx.x;
    if (i < N) {
        rowptr[i] += bsums[i >> 8];
        cnt[i] = 0;                            // becomes fill cursor
    }
    if (i == 0) rowptr[N] = E;
}

__global__ void k_fill(const int* __restrict__ srcv, const int* __restrict__ dstv,
                       const int* __restrict__ rowptr, int* __restrict__ cur,
                       int* __restrict__ csr_src, int E) {
    int e = blockIdx.x * blockDim.x + threadIdx.x;
    if (e < E) {
        const int d = dstv[e];
        const int slot = atomicAdd(&cur[d], 1);
        csr_src[rowptr[d] + slot] = srcv[e];
    }
}

__global__ void k_bounds(const int* __restrict__ batch, int N, int G,
                         int* __restrict__ start) {
    const int g = blockIdx.x * blockDim.x + threadIdx.x;
    if (g > G) return;
    int lo = 0, hi = N;
    while (lo < hi) {
        const int mid = (lo + hi) >> 1;
        if (batch[mid] < g) lo = mid + 1; else hi = mid;
    }
    start[g] = lo;
}

// Wc = W4 @ Wlin (128 x T), bc = b4 @ Wlin + blin (T)
__global__ void k_combine(const float* __restrict__ W4, const float* __restrict__ Wlin,
                          const float* __restrict__ b4, const float* __restrict__ blin,
                          float* __restrict__ Wc, float* __restrict__ bc, int T) {
    const int idx = blockIdx.x * blockDim.x + threadIdx.x;
    if (idx < 128 * T) {
        const int k = idx / T, t = idx % T;
        float acc = 0.f;
        #pragma unroll 8
        for (int j = 0; j < 128; ++j)
            acc = fmaf(W4[k * 128 + j], Wlin[j * T + t], acc);
        Wc[idx] = acc;
    }
    if (idx < T) {
        float acc = blin[idx];
        #pragma unroll 8
        for (int j = 0; j < 128; ++j)
            acc = fmaf(b4[j], Wlin[j * T + idx], acc);
        bc[idx] = acc;
    }
}

__device__ __forceinline__ void fma4(float4& acc, float s, const float4& w) {
    acc.x = fmaf(s, w.x, acc.x);
    acc.y = fmaf(s, w.y, acc.y);
    acc.z = fmaf(s, w.z, acc.z);
    acc.w = fmaf(s, w.w, acc.w);
}

// Gather aggregated rows n0 AND n1 interleaved: 8 row-loads in flight.
// Lanes past a row's end hold weight 0, so the inner loop is branch-free
// per 32-lane group (junk loads hit row 0 -> L1/L2 resident).
__device__ __forceinline__ void gather_pair(
    int n0, int n1, int v0, int v1,
    const float* __restrict__ Hin,
    const int* __restrict__ rowptr, const int* __restrict__ csr_src,
    const float* __restrict__ dinv, int lane,
    float4& r0, float4& r1)
{
    const int nc0 = v0 ? n0 : 0;
    const int nc1 = v1 ? n1 : 0;
    const float dn0 = v0 ? dinv[nc0] : 0.f;
    const float dn1 = v1 ? dinv[nc1] : 0.f;
    int c0 = rowptr[nc0];
    int c1 = rowptr[nc1];
    const int e0 = v0 ? rowptr[nc0 + 1] : c0;
    const int e1 = v1 ? rowptr[nc1 + 1] : c1;

    const float4 s0 = *(const float4*)(Hin + (size_t)nc0 * 128 + 4 * lane);
    const float4 s1 = *(const float4*)(Hin + (size_t)nc1 * 128 + 4 * lane);
    float4 p0 = make_float4(s0.x * dn0, s0.y * dn0, s0.z * dn0, s0.w * dn0);
    float4 q0 = make_float4(s1.x * dn1, s1.y * dn1, s1.z * dn1, s1.w * dn1);
    float4 p1 = make_float4(0.f, 0.f, 0.f, 0.f);
    float4 q1 = make_float4(0.f, 0.f, 0.f, 0.f);

    while (c0 < e0 || c1 < e1) {
        int sv0 = 0, sv1 = 0; float wv0 = 0.f, wv1 = 0.f;
        if (c0 + lane < e0) { sv0 = csr_src[c0 + lane]; wv0 = dinv[sv0]; }
        if (c1 + lane < e1) { sv1 = csr_src[c1 + lane]; wv1 = dinv[sv1]; }
        const int m0 = min(32, e0 - c0);      // may be <= 0 (exhausted row)
        const int m1 = min(32, e1 - c1);
        const int mm = max(m0, m1);
        for (int k = 0; k < mm; k += 4) {
            const int   i00 = __shfl(sv0, k, 32),     i01 = __shfl(sv0, k + 1, 32);
            const int   i02 = __shfl(sv0, k + 2, 32), i03 = __shfl(sv0, k + 3, 32);
            const float w00 = __shfl(wv0, k, 32),     w01 = __shfl(wv0, k + 1, 32);
            const float w02 = __shfl(wv0, k + 2, 32), w03 = __shfl(wv0, k + 3, 32);
            const int   i10 = __shfl(sv1, k, 32),     i11 = __shfl(sv1, k + 1, 32);
            const int   i12 = __shfl(sv1, k + 2, 32), i13 = __shfl(sv1, k + 3, 32);
            const float w10 = __shfl(wv1, k, 32),     w11 = __shfl(wv1, k + 1, 32);
            const float w12 = __shfl(wv1, k + 2, 32), w13 = __shfl(wv1, k + 3, 32);
            const float4 v00 = *(const float4*)(Hin + (size_t)i00 * 128 + 4 * lane);
            const float4 v01 = *(const float4*)(Hin + (size_t)i01 * 128 + 4 * lane);
            const float4 v02 = *(const float4*)(Hin + (size_t)i02 * 128 + 4 * lane);
            const float4 v03 = *(const float4*)(Hin + (size_t)i03 * 128 + 4 * lane);
            const float4 v10 = *(const float4*)(Hin + (size_t)i10 * 128 + 4 * lane);
            const float4 v11 = *(const float4*)(Hin + (size_t)i11 * 128 + 4 * lane);
            const float4 v12 = *(const float4*)(Hin + (size_t)i12 * 128 + 4 * lane);
            const float4 v13 = *(const float4*)(Hin + (size_t)i13 * 128 + 4 * lane);
            fma4(p0, w00, v00); fma4(p1, w01, v01); fma4(p0, w02, v02); fma4(p1, w03, v03);
            fma4(q0, w10, v10); fma4(q1, w11, v11); fma4(q0, w12, v12); fma4(q1, w13, v13);
        }
        c0 += 32; c1 += 32;
    }
    p0.x += p1.x; p0.y += p1.y; p0.z += p1.z; p0.w += p1.w;
    q0.x += q1.x; q0.y += q1.y; q0.z += q1.z; q0.w += q1.w;
    r0 = make_float4(p0.x * dn0, p0.y * dn0, p0.z * dn0, p0.w * dn0);
    r1 = make_float4(q0.x * dn1, q0.y * dn1, q0.z * dn1, q0.w * dn1);
}

// Fused layer: Hout[n] = act( (A·Hin)[n] @ W + bias ). One 32-row tile/block.
__global__ __launch_bounds__(512, 2) void k_layer(
    const float* __restrict__ Hin, const float* __restrict__ W,
    const float* __restrict__ bias, int dorelu,
    const int* __restrict__ rowptr, const int* __restrict__ csr_src,
    const float* __restrict__ dinv,
    float* __restrict__ Hout, int N)
{
    __shared__ float Wl[128 * 128];   // 64 KiB weights [k][c]
    __shared__ float hl[32 * 128];    // 16 KiB aggregated rows (no pad needed:
                                      // matvec reads are lane-broadcast)
    const int tid = threadIdx.x;
    for (int i = tid; i < 4096; i += 512)
        ((float4*)Wl)[i] = ((const float4*)W)[i];

    const int lane = tid & 31;
    const int grp  = tid >> 5;        // 0..15
    const int rowBase = blockIdx.x << 5;

    const int n0 = rowBase + grp;
    const int n1 = rowBase + grp + 16;
    const int v0 = n0 < N, v1 = n1 < N;
    float4 g0, g1;
    gather_pair(n0, n1, v0, v1, Hin, rowptr, csr_src, dinv, lane, g0, g1);
    if (v0) *(float4*)(hl + grp * 128 + 4 * lane) = g0;
    if (v1) *(float4*)(hl + (grp + 16) * 128 + 4 * lane) = g1;
    __syncthreads();   // hl + Wl ready

    float4 a0 = make_float4(0.f, 0.f, 0.f, 0.f);
    float4 a1 = make_float4(0.f, 0.f, 0.f, 0.f);
    #pragma unroll 4
    for (int kq = 0; kq < 32; ++kq) {
        const float4 h0 = *(const float4*)(hl + grp * 128 + 4 * kq);
        const float4 h1 = *(const float4*)(hl + (grp + 16) * 128 + 4 * kq);
        const float4* wp = ((const float4*)Wl) + kq * 128 + lane;
        const float4 w0 = wp[0];
        const float4 w1 = wp[32];
        const float4 w2 = wp[64];
        const float4 w3 = wp[96];
        fma4(a0, h0.x, w0); fma4(a0, h0.y, w1); fma4(a0, h0.z, w2); fma4(a0, h0.w, w3);
        fma4(a1, h1.x, w0); fma4(a1, h1.y, w1); fma4(a1, h1.z, w2); fma4(a1, h1.w, w3);
    }

    const float4 bv = ((const float4*)bias)[lane];
    a0.x += bv.x; a0.y += bv.y; a0.z += bv.z; a0.w += bv.w;
    a1.x += bv.x; a1.y += bv.y; a1.z += bv.z; a1.w += bv.w;
    if (dorelu) {
        a0.x = fmaxf(a0.x, 0.f); a0.y = fmaxf(a0.y, 0.f);
        a0.z = fmaxf(a0.z, 0.f); a0.w = fmaxf(a0.w, 0.f);
        a1.x = fmaxf(a1.x, 0.f); a1.y = fmaxf(a1.y, 0.f);
        a1.z = fmaxf(a1.z, 0.f); a1.w = fmaxf(a1.w, 0.f);
    }
    if (v0) *(float4*)(Hout + (size_t)n0 * 128 + 4 * lane) = a0;
    if (v1) *(float4*)(Hout + (size_t)n1 * 128 + 4 * lane) = a1;
}

// Layer 4: pure gather (matvec commuted past the mean-pool), 2 nodes/group
__global__ void k_gather4(const int* __restrict__ rowptr, const int* __restrict__ csr_src,
                          const float* __restrict__ dinv, const float* __restrict__ Hin,
                          float* __restrict__ outb, int N)
{
    const int t = blockIdx.x * blockDim.x + threadIdx.x;
    const int lane = t & 31;
    const int g = t >> 5;
    const int n0 = 2 * g, n1 = 2 * g + 1;
    if (n0 >= N) return;
    float4 r0, r1;
    gather_pair(n0, n1, 1, n1 < N, Hin, rowptr, csr_src, dinv, lane, r0, r1);
    *(float4*)(outb + (size_t)n0 * 128 + 4 * lane) = r0;
    if (n1 < N) *(float4*)(outb + (size_t)n1 * 128 + 4 * lane) = r1;
}

__global__ void k_pool_seg(const float* __restrict__ h, const int* __restrict__ start,
                           float* __restrict__ pooled)
{
    __shared__ float4 sh[8][32];
    const int g = blockIdx.x;
    const int t = threadIdx.x;
    const int lane = t & 31, grp = t >> 5;
    const int s0 = start[g], s1 = start[g + 1];

    float4 acc = make_float4(0.f, 0.f, 0.f, 0.f);
    for (int r = s0 + grp; r < s1; r += 8) {
        const float4 v = *(const float4*)(h + (size_t)r * 128 + 4 * lane);
        acc.x += v.x; acc.y += v.y; acc.z += v.z; acc.w += v.w;
    }
    sh[grp][lane] = acc;
    __syncthreads();
    if (grp == 0) {
        float4 a = sh[0][lane];
        #pragma unroll
        for (int k = 1; k < 8; ++k) {
            a.x += sh[k][lane].x; a.y += sh[k][lane].y;
            a.z += sh[k][lane].z; a.w += sh[k][lane].w;
        }
        const float inv = 1.0f / fmaxf((float)(s1 - s0), 1.0f);
        a.x *= inv; a.y *= inv; a.z *= inv; a.w *= inv;
        *(float4*)(pooled + (size_t)g * 128 + 4 * lane) = a;
    }
}

__global__ void k_final(const float* __restrict__ pooledA, const float* __restrict__ Wc,
                        const float* __restrict__ bc, float* __restrict__ out, int T)
{
    __shared__ float hv[128];
    const int g = blockIdx.x;
    const int c = threadIdx.x;
    hv[c] = pooledA[(size_t)g * 128 + c];
    __syncthreads();
    if (c < T) {
        float acc = bc[c];
        #pragma unroll
        for (int k = 0; k < 128; ++k)
            acc = fmaf(hv[k], Wc[k * T + c], acc);
        out[g * T + c] = acc;
    }
}

extern "C" void kernel_launch(void* const* d_in, const int* in_sizes, int n_in,
                              void* d_out, int out_size, void* d_ws, size_t ws_size,
                              hipStream_t stream)
{
    const float* x     = (const float*)d_in[0];
    const int*   ei    = (const int*)d_in[1];
    const int*   batch = (const int*)d_in[2];
    const float* W1    = (const float*)d_in[3];
    const float* b1    = (const float*)d_in[4];
    const float* Ws    = (const float*)d_in[5];
    const float* bs    = (const float*)d_in[6];
    const float* Wlin  = (const float*)d_in[7];
    const float* blin  = (const float*)d_in[8];
    float* out = (float*)d_out;

    const int N = in_sizes[0] / 128;
    const int E = in_sizes[1] / 2;
    const int T = in_sizes[8];           // 10
    const int G = out_size / T;          // 512

    // workspace layout (float offsets):
    float* ws = (float*)d_ws;
    int*   cnt     = (int*)ws;                       // [N] histogram -> cursor (dead after fill)
    int*   rowptr  = (int*)(ws + 50000);             // [N+1]
    int*   bsums   = (int*)(ws + 100016);            // [256]
    int*   start   = (int*)(ws + 100272);            // [G+1]
    int*   csr_src = (int*)(ws + 100800);            // [E]
    float* dinv    = ws + 740800;                    // [N]
    float* bufA    = ws + 790800;                    // [N*128]
    float* bufB    = ws + 7190800;                   // [N*128]
    float* pooledA = ws + 13590800;                  // [G*128]
    float* Wc      = ws + 24000;                     // reuse cnt region (dead), [128*T]
    float* bc      = ws + 24000 + 128 * 10;          // [T]

    const int* srcs = ei;
    const int* dsts = ei + E;
    const float* W4 = Ws + 2 * 16384;
    const float* b4 = bs + 2 * 128;

    hipMemsetAsync(cnt, 0, (size_t)N * sizeof(int), stream);

    const int nb = (N + 255) / 256;
    k_count <<<(E + 255) / 256, 256, 0, stream>>>(dsts, E, cnt);
    k_scan1 <<<nb, 256, 0, stream>>>(cnt, N, rowptr, bsums, dinv);
    k_scan2 <<<1, 256, 0, stream>>>(bsums, nb);
    k_scan3 <<<nb, 256, 0, stream>>>(rowptr, bsums, cnt, N, E);
    k_fill  <<<(E + 255) / 256, 256, 0, stream>>>(srcs, dsts, rowptr, cnt, csr_src, E);
    k_bounds<<<(G + 256) / 256, 256, 0, stream>>>(batch, N, G, start);
    // cnt region dead from here; Wc/bc overlap it (k_combine runs after k_fill)
    k_combine<<<(128 * T + 255) / 256, 256, 0, stream>>>(W4, Wlin, b4, blin, Wc, bc, T);

    const int layerBlocks = (N + 31) / 32;   // 1563, one 32-row tile each

    k_layer<<<layerBlocks, 512, 0, stream>>>(x,    W1,         b1,       1, rowptr, csr_src, dinv, bufA, N);
    k_layer<<<layerBlocks, 512, 0, stream>>>(bufA, Ws,         bs,       1, rowptr, csr_src, dinv, bufB, N);
    k_layer<<<layerBlocks, 512, 0, stream>>>(bufB, Ws + 16384, bs + 128, 1, rowptr, csr_src, dinv, bufA, N);
    // layer 4: gather only
    k_gather4<<<((N + 1) / 2 * 32 + 255) / 256, 256, 0, stream>>>(rowptr, csr_src, dinv, bufA, bufB, N);

    k_pool_seg<<<G, 256, 0, stream>>>(bufB, start, pooledA);
    k_final   <<<G, 128, 0, stream>>>(pooledA, Wc, bc, out, T);
}

// Round 6
// 369.068 us; speedup vs baseline: 12.4453x; 1.0006x over previous
//
#include <hip/hip_runtime.h>

// ---------------------------------------------------------------------------
// GCN forward, pull-based + fused. A(HW) = (AH)W:
//   per layer one kernel: gather A·H rows into LDS (lane-uniform CSR reads,
//   precomputed edge weights, no shuffles), then 128x128 matvec with W staged
//   in two 32 KiB halves (48 KiB LDS/block -> 3 blocks/CU). Layer 4's matvec
//   commutes past the mean-pool: out = mean(agg4)·(W4·Wlin) + (b4·Wlin+blin).
// ---------------------------------------------------------------------------

__global__ void k_count(const int* __restrict__ dstv, int E, int* __restrict__ cnt) {
    int e = blockIdx.x * blockDim.x + threadIdx.x;
    if (e < E) atomicAdd(&cnt[dstv[e]], 1);
}

// scan1 also emits dinv (cnt still pristine here)
__global__ void k_scan1(const int* __restrict__ cnt, int N,
                        int* __restrict__ rowptr, int* __restrict__ bsums,
                        float* __restrict__ dinv) {
    __shared__ int sh[256];
    const int t = threadIdx.x;
    const int i = blockIdx.x * 256 + t;
    const int v = (i < N) ? cnt[i] : 0;
    if (i < N) dinv[i] = 1.0f / sqrtf((float)(v + 1));  // +1 self loop
    sh[t] = v;
    __syncthreads();
    for (int off = 1; off < 256; off <<= 1) {
        int add = (t >= off) ? sh[t - off] : 0;
        __syncthreads();
        sh[t] += add;
        __syncthreads();
    }
    if (i < N) rowptr[i] = sh[t] - v;
    if (t == 255) bsums[blockIdx.x] = sh[255];
}

__global__ void k_scan2(int* __restrict__ bsums, int nb) {
    __shared__ int sh[256];
    const int t = threadIdx.x;
    const int v = (t < nb) ? bsums[t] : 0;
    sh[t] = v;
    __syncthreads();
    for (int off = 1; off < 256; off <<= 1) {
        int add = (t >= off) ? sh[t - off] : 0;
        __syncthreads();
        sh[t] += add;
        __syncthreads();
    }
    if (t < nb) bsums[t] = sh[t] - v;
}

__global__ void k_scan3(int* __restrict__ rowptr, const int* __restrict__ bsums,
                        int* __restrict__ cnt, int N, int E) {
    const int i = blockIdx.x * blockDim.x + threadIdx.x;
    if (i < N) {
        rowptr[i] += bsums[i >> 8];
        cnt[i] = 0;                            // becomes fill cursor
    }
    if (i == 0) rowptr[N] = E;
}

// also writes fused edge weight dinv[src]*dinv[dst]
__global__ void k_fill(const int* __restrict__ srcv, const int* __restrict__ dstv,
                       const int* __restrict__ rowptr, int* __restrict__ cur,
                       const float* __restrict__ dinv,
                       int* __restrict__ csr_src, float* __restrict__ csr_w, int E) {
    int e = blockIdx.x * blockDim.x + threadIdx.x;
    if (e < E) {
        const int d = dstv[e];
        const int s = srcv[e];
        const int slot = atomicAdd(&cur[d], 1);
        const int p = rowptr[d] + slot;
        csr_src[p] = s;
        csr_w[p] = dinv[s] * dinv[d];
    }
}

__global__ void k_bounds(const int* __restrict__ batch, int N, int G,
                         int* __restrict__ start) {
    const int g = blockIdx.x * blockDim.x + threadIdx.x;
    if (g > G) return;
    int lo = 0, hi = N;
    while (lo < hi) {
        const int mid = (lo + hi) >> 1;
        if (batch[mid] < g) lo = mid + 1; else hi = mid;
    }
    start[g] = lo;
}

// Wc = W4 @ Wlin (128 x T), bc = b4 @ Wlin + blin (T)
__global__ void k_combine(const float* __restrict__ W4, const float* __restrict__ Wlin,
                          const float* __restrict__ b4, const float* __restrict__ blin,
                          float* __restrict__ Wc, float* __restrict__ bc, int T) {
    const int idx = blockIdx.x * blockDim.x + threadIdx.x;
    if (idx < 128 * T) {
        const int k = idx / T, t = idx % T;
        float acc = 0.f;
        #pragma unroll 8
        for (int j = 0; j < 128; ++j)
            acc = fmaf(W4[k * 128 + j], Wlin[j * T + t], acc);
        Wc[idx] = acc;
    }
    if (idx < T) {
        float acc = blin[idx];
        #pragma unroll 8
        for (int j = 0; j < 128; ++j)
            acc = fmaf(b4[j], Wlin[j * T + idx], acc);
        bc[idx] = acc;
    }
}

__device__ __forceinline__ void fma4(float4& acc, float s, const float4& w) {
    acc.x = fmaf(s, w.x, acc.x);
    acc.y = fmaf(s, w.y, acc.y);
    acc.z = fmaf(s, w.z, acc.z);
    acc.w = fmaf(s, w.w, acc.w);
}

// Aggregated row n, column slice [4*lane, 4*lane+4). No shuffles: all 32
// lanes read the same csr_src/csr_w address (hardware broadcast), so load
// addresses are pure induction variables -> deep load pipelining.
__device__ __forceinline__ float4 gather_row(
    int n, const float* __restrict__ Hin,
    const int* __restrict__ rowptr, const int* __restrict__ csr_src,
    const float* __restrict__ csr_w, const float* __restrict__ dinv, int lane)
{
    const float dn = dinv[n];
    const float sw = dn * dn;
    const float4 self = *(const float4*)(Hin + (size_t)n * 128 + 4 * lane);
    float4 a0 = make_float4(self.x * sw, self.y * sw, self.z * sw, self.w * sw);
    float4 a1 = make_float4(0.f, 0.f, 0.f, 0.f);
    float4 a2 = a1, a3 = a1;
    const int beg = rowptr[n], end = rowptr[n + 1];
    int j = beg;
    for (; j + 4 <= end; j += 4) {
        const int   s0 = csr_src[j],     s1 = csr_src[j + 1];
        const int   s2 = csr_src[j + 2], s3 = csr_src[j + 3];
        const float w0 = csr_w[j],       w1 = csr_w[j + 1];
        const float w2 = csr_w[j + 2],   w3 = csr_w[j + 3];
        const float4 v0 = *(const float4*)(Hin + (size_t)s0 * 128 + 4 * lane);
        const float4 v1 = *(const float4*)(Hin + (size_t)s1 * 128 + 4 * lane);
        const float4 v2 = *(const float4*)(Hin + (size_t)s2 * 128 + 4 * lane);
        const float4 v3 = *(const float4*)(Hin + (size_t)s3 * 128 + 4 * lane);
        fma4(a0, w0, v0); fma4(a1, w1, v1); fma4(a2, w2, v2); fma4(a3, w3, v3);
    }
    for (; j < end; ++j) {
        const int   s = csr_src[j];
        const float w = csr_w[j];
        const float4 v = *(const float4*)(Hin + (size_t)s * 128 + 4 * lane);
        fma4(a0, w, v);
    }
    a0.x += a1.x + a2.x + a3.x;
    a0.y += a1.y + a2.y + a3.y;
    a0.z += a1.z + a2.z + a3.z;
    a0.w += a1.w + a2.w + a3.w;
    return a0;
}

// Fused layer: Hout[n] = relu( (A·Hin)[n] @ W + bias ). One 32-row tile/block.
// W staged in two 64x128 halves; accumulators live across both passes.
__global__ __launch_bounds__(512, 6) void k_layer(
    const float* __restrict__ Hin, const float* __restrict__ W,
    const float* __restrict__ bias,
    const int* __restrict__ rowptr, const int* __restrict__ csr_src,
    const float* __restrict__ csr_w, const float* __restrict__ dinv,
    float* __restrict__ Hout, int N)
{
    __shared__ float Wl[64 * 128];    // 32 KiB: half of W [k][c]
    __shared__ float hl[32 * 128];    // 16 KiB: 32 aggregated rows
    const int tid = threadIdx.x;
    for (int i = tid; i < 2048; i += 512)
        ((float4*)Wl)[i] = ((const float4*)W)[i];          // rows 0..63

    const int lane = tid & 31;
    const int grp  = tid >> 5;        // 0..15
    const int rowBase = blockIdx.x << 5;

    const int n0 = rowBase + grp;
    const int n1 = rowBase + grp + 16;
    if (n0 < N) {
        const float4 g = gather_row(n0, Hin, rowptr, csr_src, csr_w, dinv, lane);
        *(float4*)(hl + grp * 128 + 4 * lane) = g;
    }
    if (n1 < N) {
        const float4 g = gather_row(n1, Hin, rowptr, csr_src, csr_w, dinv, lane);
        *(float4*)(hl + (grp + 16) * 128 + 4 * lane) = g;
    }
    __syncthreads();   // hl + Wl(half 0) ready

    float4 a0 = make_float4(0.f, 0.f, 0.f, 0.f);
    float4 a1 = make_float4(0.f, 0.f, 0.f, 0.f);
    // pass 0: k = 0..63
    #pragma unroll 4
    for (int kq = 0; kq < 16; ++kq) {
        const float4 h0 = *(const float4*)(hl + grp * 128 + 4 * kq);
        const float4 h1 = *(const float4*)(hl + (grp + 16) * 128 + 4 * kq);
        const float4* wp = ((const float4*)Wl) + (4 * kq) * 32 + lane;
        const float4 w0 = wp[0];
        const float4 w1 = wp[32];
        const float4 w2 = wp[64];
        const float4 w3 = wp[96];
        fma4(a0, h0.x, w0); fma4(a0, h0.y, w1); fma4(a0, h0.z, w2); fma4(a0, h0.w, w3);
        fma4(a1, h1.x, w0); fma4(a1, h1.y, w1); fma4(a1, h1.z, w2); fma4(a1, h1.w, w3);
    }
    __syncthreads();   // pass-0 Wl reads done
    for (int i = tid; i < 2048; i += 512)
        ((float4*)Wl)[i] = ((const float4*)(W + 64 * 128))[i];  // rows 64..127
    __syncthreads();   // Wl(half 1) ready
    // pass 1: k = 64..127
    #pragma unroll 4
    for (int kq = 0; kq < 16; ++kq) {
        const float4 h0 = *(const float4*)(hl + grp * 128 + 64 + 4 * kq);
        const float4 h1 = *(const float4*)(hl + (grp + 16) * 128 + 64 + 4 * kq);
        const float4* wp = ((const float4*)Wl) + (4 * kq) * 32 + lane;
        const float4 w0 = wp[0];
        const float4 w1 = wp[32];
        const float4 w2 = wp[64];
        const float4 w3 = wp[96];
        fma4(a0, h0.x, w0); fma4(a0, h0.y, w1); fma4(a0, h0.z, w2); fma4(a0, h0.w, w3);
        fma4(a1, h1.x, w0); fma4(a1, h1.y, w1); fma4(a1, h1.z, w2); fma4(a1, h1.w, w3);
    }

    const float4 bv = ((const float4*)bias)[lane];
    a0.x += bv.x; a0.y += bv.y; a0.z += bv.z; a0.w += bv.w;
    a1.x += bv.x; a1.y += bv.y; a1.z += bv.z; a1.w += bv.w;
    a0.x = fmaxf(a0.x, 0.f); a0.y = fmaxf(a0.y, 0.f);
    a0.z = fmaxf(a0.z, 0.f); a0.w = fmaxf(a0.w, 0.f);
    a1.x = fmaxf(a1.x, 0.f); a1.y = fmaxf(a1.y, 0.f);
    a1.z = fmaxf(a1.z, 0.f); a1.w = fmaxf(a1.w, 0.f);
    if (n0 < N) *(float4*)(Hout + (size_t)n0 * 128 + 4 * lane) = a0;
    if (n1 < N) *(float4*)(Hout + (size_t)n1 * 128 + 4 * lane) = a1;
}

// Layer 4: pure gather (matvec commuted past the mean-pool)
__global__ void k_gather4(const int* __restrict__ rowptr, const int* __restrict__ csr_src,
                          const float* __restrict__ csr_w, const float* __restrict__ dinv,
                          const float* __restrict__ Hin,
                          float* __restrict__ outb, int N)
{
    const int t = blockIdx.x * blockDim.x + threadIdx.x;
    const int lane = t & 31;
    const int n = t >> 5;
    if (n >= N) return;
    const float4 r = gather_row(n, Hin, rowptr, csr_src, csr_w, dinv, lane);
    *(float4*)(outb + (size_t)n * 128 + 4 * lane) = r;
}

__global__ void k_pool_seg(const float* __restrict__ h, const int* __restrict__ start,
                           float* __restrict__ pooled)
{
    __shared__ float4 sh[8][32];
    const int g = blockIdx.x;
    const int t = threadIdx.x;
    const int lane = t & 31, grp = t >> 5;
    const int s0 = start[g], s1 = start[g + 1];

    float4 acc = make_float4(0.f, 0.f, 0.f, 0.f);
    for (int r = s0 + grp; r < s1; r += 8) {
        const float4 v = *(const float4*)(h + (size_t)r * 128 + 4 * lane);
        acc.x += v.x; acc.y += v.y; acc.z += v.z; acc.w += v.w;
    }
    sh[grp][lane] = acc;
    __syncthreads();
    if (grp == 0) {
        float4 a = sh[0][lane];
        #pragma unroll
        for (int k = 1; k < 8; ++k) {
            a.x += sh[k][lane].x; a.y += sh[k][lane].y;
            a.z += sh[k][lane].z; a.w += sh[k][lane].w;
        }
        const float inv = 1.0f / fmaxf((float)(s1 - s0), 1.0f);
        a.x *= inv; a.y *= inv; a.z *= inv; a.w *= inv;
        *(float4*)(pooled + (size_t)g * 128 + 4 * lane) = a;
    }
}

__global__ void k_final(const float* __restrict__ pooledA, const float* __restrict__ Wc,
                        const float* __restrict__ bc, float* __restrict__ out, int T)
{
    __shared__ float hv[128];
    const int g = blockIdx.x;
    const int c = threadIdx.x;
    hv[c] = pooledA[(size_t)g * 128 + c];
    __syncthreads();
    if (c < T) {
        float acc = bc[c];
        #pragma unroll
        for (int k = 0; k < 128; ++k)
            acc = fmaf(hv[k], Wc[k * T + c], acc);
        out[g * T + c] = acc;
    }
}

extern "C" void kernel_launch(void* const* d_in, const int* in_sizes, int n_in,
                              void* d_out, int out_size, void* d_ws, size_t ws_size,
                              hipStream_t stream)
{
    const float* x     = (const float*)d_in[0];
    const int*   ei    = (const int*)d_in[1];
    const int*   batch = (const int*)d_in[2];
    const float* W1    = (const float*)d_in[3];
    const float* b1    = (const float*)d_in[4];
    const float* Ws    = (const float*)d_in[5];
    const float* bs    = (const float*)d_in[6];
    const float* Wlin  = (const float*)d_in[7];
    const float* blin  = (const float*)d_in[8];
    float* out = (float*)d_out;

    const int N = in_sizes[0] / 128;
    const int E = in_sizes[1] / 2;
    const int T = in_sizes[8];           // 10
    const int G = out_size / T;          // 512

    // workspace layout (float offsets):
    float* ws = (float*)d_ws;
    int*   cnt     = (int*)ws;                       // [N] histogram -> cursor (dead after fill)
    int*   rowptr  = (int*)(ws + 50000);             // [N+1]
    int*   bsums   = (int*)(ws + 100016);            // [256]
    int*   start   = (int*)(ws + 100272);            // [G+1]
    int*   csr_src = (int*)(ws + 100800);            // [E]
    float* csr_w   = ws + 740800;                    // [E]
    float* dinv    = ws + 1380800;                   // [N]
    float* bufA    = ws + 1430816;                   // [N*128]
    float* bufB    = ws + 7830816;                   // [N*128]
    float* pooledA = ws + 14230816;                  // [G*128]
    float* Wc      = ws + 24000;                     // reuse cnt region (dead), [128*T]
    float* bc      = ws + 24000 + 128 * 10;          // [T]

    const int* srcs = ei;
    const int* dsts = ei + E;
    const float* W4 = Ws + 2 * 16384;
    const float* b4 = bs + 2 * 128;

    hipMemsetAsync(cnt, 0, (size_t)N * sizeof(int), stream);

    const int nb = (N + 255) / 256;
    k_count <<<(E + 255) / 256, 256, 0, stream>>>(dsts, E, cnt);
    k_scan1 <<<nb, 256, 0, stream>>>(cnt, N, rowptr, bsums, dinv);
    k_scan2 <<<1, 256, 0, stream>>>(bsums, nb);
    k_scan3 <<<nb, 256, 0, stream>>>(rowptr, bsums, cnt, N, E);
    k_fill  <<<(E + 255) / 256, 256, 0, stream>>>(srcs, dsts, rowptr, cnt, dinv, csr_src, csr_w, E);
    k_bounds<<<(G + 256) / 256, 256, 0, stream>>>(batch, N, G, start);
    // cnt region dead from here; Wc/bc overlap it (k_combine runs after k_fill)
    k_combine<<<(128 * T + 255) / 256, 256, 0, stream>>>(W4, Wlin, b4, blin, Wc, bc, T);

    const int layerBlocks = (N + 31) / 32;   // 1563, one 32-row tile each

    k_layer<<<layerBlocks, 512, 0, stream>>>(x,    W1,         b1,       rowptr, csr_src, csr_w, dinv, bufA, N);
    k_layer<<<layerBlocks, 512, 0, stream>>>(bufA, Ws,         bs,       rowptr, csr_src, csr_w, dinv, bufB, N);
    k_layer<<<layerBlocks, 512, 0, stream>>>(bufB, Ws + 16384, bs + 128, rowptr, csr_src, csr_w, dinv, bufA, N);
    // layer 4: gather only
    k_gather4<<<(N * 32 + 255) / 256, 256, 0, stream>>>(rowptr, csr_src, csr_w, dinv, bufA, bufB, N);

    k_pool_seg<<<G, 256, 0, stream>>>(bufB, start, pooledA);
    k_final   <<<G, 128, 0, stream>>>(pooledA, Wc, bc, out, T);
}